// Round 9
// baseline (2263.145 us; speedup 1.0000x reference)
//
#include <hip/hip_runtime.h>

#define GAMMA 0.99f
#define LAM   0.95f

constexpr int SEG   = 256;     // columns per segment (one wave's tile)
constexpr int WPB   = 4;       // waves per block
constexpr int BLOCK = WPB * 64;

// A 256-col segment's affine multiplier M = prod(c) <= (GAMMA*LAM)^256 ~ 1.5e-7,
// so g entering segment s equals the right neighbor's zero-initialized segment
// total A(s+1) to within ~2e-6 absolute — one-hop truncation of the scan chain.

__device__ __forceinline__ void seg_delta_c(
    const float* __restrict__ rewards, const float* __restrict__ values,
    const float* __restrict__ next_value, const int* __restrict__ done,
    int row, int seg, int lane, int T,
    float delta[4], float c[4], float4& vv_out)
{
    const long rowbase = (long)row * T;
    const int  col0    = seg * SEG + lane * 4;

    const float4 rv = *reinterpret_cast<const float4*>(rewards + rowbase + col0);
    const float4 vv = *reinterpret_cast<const float4*>(values  + rowbase + col0);
    const int4   dv = *reinterpret_cast<const int4*>(done      + rowbase + col0);

    float bv = 0.0f; float bd = 0.0f;
    if (lane == 63) {
        const int E = seg * SEG + SEG;
        if (E < T) { bv = values[rowbase + E]; bd = (float)done[rowbase + E]; }
        else       { bv = next_value[row];     bd = (float)dv.w; }
    }
    const float v_nb = __shfl_down(vv.x, 1);
    const float d_nb = (float)__shfl_down(dv.x, 1);
    const float vnext = (lane == 63) ? bv : v_nb;
    const float dnext = (lane == 63) ? bd : d_nb;

    const float n0 = 1.0f - (float)dv.y;
    const float n1 = 1.0f - (float)dv.z;
    const float n2 = 1.0f - (float)dv.w;
    const float n3 = 1.0f - dnext;
    delta[0] = rv.x + GAMMA * vv.y  * n0 - vv.x;
    delta[1] = rv.y + GAMMA * vv.z  * n1 - vv.y;
    delta[2] = rv.z + GAMMA * vv.w  * n2 - vv.z;
    delta[3] = rv.w + GAMMA * vnext * n3 - vv.w;
    c[0] = (GAMMA * LAM) * n0;
    c[1] = (GAMMA * LAM) * n1;
    c[2] = (GAMMA * LAM) * n2;
    c[3] = (GAMMA * LAM) * n3;
    vv_out = vv;
}

__device__ __forceinline__ void suffix_scan(int lane, float& sa, float& sm)
{
#pragma unroll
    for (int d = 1; d < 64; d <<= 1) {
        float oa = __shfl_down(sa, d);
        float om = __shfl_down(sm, d);
        if (lane + d < 64) { sa = sa + sm * oa; sm = sm * om; }
    }
}

// Zero the ready-flags each iteration (ws is poison-filled by the harness;
// this kernel is graph-ordered before the main kernel on the same stream).
__global__ void gae_init_flags(int* __restrict__ flag, int n)
{
    const int i = blockIdx.x * blockDim.x + threadIdx.x;
    if (i < n) flag[i] = 0;
}

// One wave per 256-col segment. Own scan -> publish total -> one-shot probe
// of right neighbor's total (bounded spin, compute-fallback: deadlock-free,
// no dispatch-order assumption) -> replay -> store. No LDS, no barriers.
__global__ __launch_bounds__(BLOCK) void gae_lb_kernel(
    const float* __restrict__ rewards, const float* __restrict__ values,
    const float* __restrict__ next_value, const int* __restrict__ done,
    float* __restrict__ A, int* __restrict__ flag,
    float* __restrict__ adv_out, float* __restrict__ ret_out,
    int B, int T)
{
    const int S    = T / SEG;
    const int gw   = blockIdx.x * WPB + (threadIdx.x >> 6);
    const int lane = threadIdx.x & 63;
    if (gw >= B * S) return;            // wave-uniform
    const int row = gw / S;
    const int seg = (S - 1) - (gw % S); // descending: producers dispatch first

    float delta[4], c[4]; float4 vv;
    seg_delta_c(rewards, values, next_value, done, row, seg, lane, T, delta, c, vv);

    float a = 0.0f, m = 1.0f;
#pragma unroll
    for (int j = 3; j >= 0; --j) { a = delta[j] + c[j] * a; m = c[j] * m; }

    float sa = a, sm = m;
    suffix_scan(lane, sa, sm);

    // ---- publish this segment's total for the left neighbor ----
    const long sid = (long)row * S + seg;
    if (seg > 0 && lane == 0) A[sid] = sa;
    __threadfence();                    // device-scope: cross-XCD safe
    if (seg > 0 && lane == 0)
        __hip_atomic_store(flag + sid, 1, __ATOMIC_RELEASE, __HIP_MEMORY_SCOPE_AGENT);

    float ea = __shfl_down(sa, 1);      // exclusive-within-wave
    float em = __shfl_down(sm, 1);
    if (lane == 63) { ea = 0.0f; em = 1.0f; }

    // ---- g entering this segment = right neighbor's total (one-hop) ----
    float g = 0.0f;
    if (seg + 1 < S) {
        int got = 0; float gA = 0.0f;
        if (lane == 0) {
            const long nid = sid + 1;
#pragma unroll 1
            for (int it = 0; it < 32; ++it) {
                if (__hip_atomic_load(flag + nid, __ATOMIC_ACQUIRE,
                                      __HIP_MEMORY_SCOPE_AGENT)) { got = 1; break; }
                __builtin_amdgcn_s_sleep(2);
            }
            if (got) gA = A[nid];
        }
        if (__shfl(got, 0)) {
            g = __shfl(gA, 0);
        } else {
            // fallback: compute neighbor's total ourselves (3KB read, ~600cy)
            float d2[4], c2[4]; float4 dum;
            seg_delta_c(rewards, values, next_value, done, row, seg + 1, lane, T,
                        d2, c2, dum);
            float a2 = 0.0f, m2 = 1.0f;
#pragma unroll
            for (int j = 3; j >= 0; --j) { a2 = d2[j] + c2[j] * a2; m2 = c2[j] * m2; }
            float s2a = a2, s2m = m2;
            suffix_scan(lane, s2a, s2m);
            g = __shfl(s2a, 0);
        }
    }
    float gin = ea + em * g;

    // ---- replay: exact sequential recurrence over the 4 owned columns ----
#pragma unroll
    for (int j = 3; j >= 0; --j) {
        gin = delta[j] + c[j] * gin;
        delta[j] = gin;                 // delta[] now holds advantages
    }

    const long rowbase = (long)row * T;
    const int  col0    = seg * SEG + lane * 4;
    float4* a4 = reinterpret_cast<float4*>(adv_out + rowbase + col0);
    float4* t4 = reinterpret_cast<float4*>(ret_out + rowbase + col0);
    *a4 = make_float4(delta[0], delta[1], delta[2], delta[3]);
    *t4 = make_float4(delta[0] + vv.x, delta[1] + vv.y,
                      delta[2] + vv.z, delta[3] + vv.w);
}

// Fallback: one thread per row, sequential (any shape / tiny workspace).
__global__ void gae_naive_kernel(
    const float* __restrict__ rewards,
    const float* __restrict__ values,
    const float* __restrict__ next_value,
    const int*   __restrict__ done,
    float* __restrict__ adv_out,
    float* __restrict__ ret_out,
    int B, int T)
{
    int row = blockIdx.x * blockDim.x + threadIdx.x;
    if (row >= B) return;
    long base = (long)row * T;
    float g = 0.0f;
    for (int t = T - 1; t >= 0; --t) {
        int dcol = (t + 1 < T) ? (t + 1) : (T - 1);
        float nnt = 1.0f - (float)done[base + dcol];
        float nv  = (t + 1 < T) ? values[base + t + 1] : next_value[row];
        float dl  = rewards[base + t] + GAMMA * nv * nnt - values[base + t];
        g = dl + (GAMMA * LAM) * nnt * g;
        adv_out[base + t] = g;
        ret_out[base + t] = g + values[base + t];
    }
}

extern "C" void kernel_launch(void* const* d_in, const int* in_sizes, int n_in,
                              void* d_out, int out_size, void* d_ws, size_t ws_size,
                              hipStream_t stream) {
    const float* rewards    = (const float*)d_in[0];
    const float* values     = (const float*)d_in[1];
    const float* next_value = (const float*)d_in[2];
    const int*   done       = (const int*)d_in[3];

    const int B = in_sizes[2];               // next_value is [B]
    const int T = in_sizes[0] / B;           // rewards is [B, T]

    float* adv = (float*)d_out;
    float* ret = adv + (long)B * T;

    const long   nseg    = (T % SEG == 0 && T >= 2 * SEG) ? (long)B * (T / SEG) : 0;
    const size_t ws_need = (size_t)nseg * (sizeof(float) + sizeof(int));

    if (nseg > 0 && ws_size >= ws_need) {
        float* Asum = (float*)d_ws;
        int*   flag = (int*)(Asum + nseg);
        const int iblocks = (int)((nseg + 255) / 256);
        gae_init_flags<<<iblocks, 256, 0, stream>>>(flag, (int)nseg);
        const int blocks = (int)((nseg + WPB - 1) / WPB);
        gae_lb_kernel<<<blocks, BLOCK, 0, stream>>>(
            rewards, values, next_value, done, Asum, flag, adv, ret, B, T);
    } else {
        gae_naive_kernel<<<(B + 255) / 256, 256, 0, stream>>>(
            rewards, values, next_value, done, adv, ret, B, T);
    }
}

// Round 11
// 146.627 us; speedup vs baseline: 15.4347x; 15.4347x over previous
//
#include <hip/hip_runtime.h>

#define GAMMA 0.99f
#define LAM   0.95f

constexpr int BLOCK  = 512;          // 8 waves
constexpr int CHUNK  = 4;            // timesteps per thread; requires T == BLOCK*CHUNK
constexpr int NWAVES = BLOCK / 64;
constexpr int GRID_TARGET = 1024;    // 4 blocks/CU on 256 CUs -> 32 waves/CU resident

// Best harness-verified configuration (146.9us bench; 45.8us best dispatch).
// Evidence ledger (R0-R10): all fused structures (any wave count, sync
// shape, prefetch depth, store policy, issue rhythm) land at 46-52us with
// FETCH=49.3MB/WRITE=65.5MB; only direction-pure phases run faster (pure
// read 4.4TB/s, pure write 6.5TB/s) but every combination mechanism
// (split re-read, flag handshake, grid.sync) costs more than it saves or
// violates graph capture. This is the fixed point.

struct RowRegs {
    float4 ra, va;
    int4   da;
    float  bv;    // values[col0+CHUNK]            (lane 63 only)
    int    bd;    // done[min(col0+CHUNK, T-1)]    (lane 63 only)
    float  vboot; // next_value[row]               (tid == BLOCK-1 only)
};

__device__ __forceinline__ void load_row(
    const float* __restrict__ rewards, const float* __restrict__ values,
    const float* __restrict__ next_value, const int* __restrict__ done,
    int row, int T, int col0, int lane, int tid, RowRegs& R)
{
    const long rowbase = (long)row * T;
    R.ra = *reinterpret_cast<const float4*>(rewards + rowbase + col0);
    R.va = *reinterpret_cast<const float4*>(values  + rowbase + col0);
    R.da = *reinterpret_cast<const int4*>(done      + rowbase + col0);
    if (lane == 63) {
        const int bcol = (col0 + CHUNK < T) ? (col0 + CHUNK) : (T - 1);
        R.bv = values[rowbase + bcol];
        R.bd = done[rowbase + bcol];
    }
    if (tid == BLOCK - 1) R.vboot = next_value[row];
}

// One block per row-group (persistent over rows {bid + k*grid}). Backward
// linear recurrence g[t] = delta[t] + c[t]*g[t+1] via affine composition:
// per-thread 4-deep compose, 64-lane wave suffix-scan, 8-wave LDS combine.
__global__ __launch_bounds__(BLOCK, 8) void gae_scan_kernel(
    const float* __restrict__ rewards,
    const float* __restrict__ values,
    const float* __restrict__ next_value,
    const int*   __restrict__ done,
    float* __restrict__ adv_out,
    float* __restrict__ ret_out,
    int B, int T)
{
    const int tid  = threadIdx.x;
    const int lane = tid & 63;
    const int wave = tid >> 6;
    const int col0 = tid * CHUNK;

    __shared__ float lds_a[2][NWAVES];
    __shared__ float lds_m[2][NWAVES];

    RowRegs cur, nxt;
    load_row(rewards, values, next_value, done, blockIdx.x, T, col0, lane, tid, cur);

    int parity = 0;
    for (int row = blockIdx.x; row < B; row += gridDim.x) {
        // ---- prefetch next row while we compute this one ----
        const int nrow = row + gridDim.x;
        if (nrow < B)
            load_row(rewards, values, next_value, done, nrow, T, col0, lane, tid, nxt);

        const long rowbase = (long)row * T;

        // ---- unpack current row ----
        float v[CHUNK], r[CHUNK];
        v[0]=cur.va.x; v[1]=cur.va.y; v[2]=cur.va.z; v[3]=cur.va.w;
        r[0]=cur.ra.x; r[1]=cur.ra.y; r[2]=cur.ra.z; r[3]=cur.ra.w;

        // neighbor thread's first elements via intra-wave shuffle
        const float v_nb = __shfl_down(cur.va.x, 1);
        const int   d_nb = __shfl_down(cur.da.x, 1);
        float vnext  = (lane == 63) ? cur.bv : v_nb;          // values[col0+CHUNK]
        float dnextf = (float)((lane == 63) ? cur.bd : d_nb); // done[col0+CHUNK]
        if (tid == BLOCK - 1) vnext = cur.vboot;              // bootstrap at t=T-1

        // done[tcol+1] per owned tcol (in-register shift of the int4)
        float dn[CHUNK];
        dn[0]=(float)cur.da.y; dn[1]=(float)cur.da.z; dn[2]=(float)cur.da.w; dn[3]=dnextf;
        float nv[CHUNK];
        nv[0]=v[1]; nv[1]=v[2]; nv[2]=v[3]; nv[3]=vnext;

        // ---- delta[t] and c[t] ----
        float delta[CHUNK], c[CHUNK];
#pragma unroll
        for (int j = 0; j < CHUNK; ++j) {
            const float nnt = 1.0f - dn[j];
            delta[j] = r[j] + GAMMA * nv[j] * nnt - v[j];
            c[j]     = (GAMMA * LAM) * nnt;
        }

        // ---- per-thread affine composition over the chunk (backward) ----
        float a = 0.0f, m = 1.0f;
#pragma unroll
        for (int j = CHUNK - 1; j >= 0; --j) {
            a = delta[j] + c[j] * a;
            m = c[j] * m;
        }

        // ---- wave-level inclusive SUFFIX scan of affine fns ----
        float sa = a, sm = m;
#pragma unroll
        for (int d = 1; d < 64; d <<= 1) {
            float oa = __shfl_down(sa, d);
            float om = __shfl_down(sm, d);
            if (lane + d < 64) { sa = sa + sm * oa; sm = sm * om; }
        }
        float ea = __shfl_down(sa, 1);   // exclusive-within-wave
        float em = __shfl_down(sm, 1);
        if (lane == 63) { ea = 0.0f; em = 1.0f; }

        // ---- cross-wave composition via parity-buffered LDS ----
        if (lane == 0) { lds_a[parity][wave] = sa; lds_m[parity][wave] = sm; }
        __syncthreads();
        float g = 0.0f;
        for (int j = NWAVES - 1; j > wave; --j)
            g = lds_a[parity][j] + lds_m[parity][j] * g;
        float gin = ea + em * g;         // gae entering this thread's chunk

        // ---- replay: exact sequential recurrence over the chunk ----
#pragma unroll
        for (int j = CHUNK - 1; j >= 0; --j) {
            gin = delta[j] + c[j] * gin;
            delta[j] = gin;              // delta[] now holds advantages
        }

        // ---- lane-contiguous vectorized stores ----
        float4* a4 = reinterpret_cast<float4*>(adv_out + rowbase + col0);
        float4* t4 = reinterpret_cast<float4*>(ret_out + rowbase + col0);
        *a4 = make_float4(delta[0], delta[1], delta[2], delta[3]);
        *t4 = make_float4(delta[0]+v[0], delta[1]+v[1], delta[2]+v[2], delta[3]+v[3]);

        parity ^= 1;
        cur = nxt;   // register move; dead after the last row
    }
}

// Fallback for shapes where T != BLOCK*CHUNK: one thread per row, sequential.
__global__ void gae_naive_kernel(
    const float* __restrict__ rewards,
    const float* __restrict__ values,
    const float* __restrict__ next_value,
    const int*   __restrict__ done,
    float* __restrict__ adv_out,
    float* __restrict__ ret_out,
    int B, int T)
{
    int row = blockIdx.x * blockDim.x + threadIdx.x;
    if (row >= B) return;
    long base = (long)row * T;
    float g = 0.0f;
    for (int t = T - 1; t >= 0; --t) {
        int dcol = (t + 1 < T) ? (t + 1) : (T - 1);
        float nnt = 1.0f - (float)done[base + dcol];
        float nv  = (t + 1 < T) ? values[base + t + 1] : next_value[row];
        float dl  = rewards[base + t] + GAMMA * nv * nnt - values[base + t];
        g = dl + (GAMMA * LAM) * nnt * g;
        adv_out[base + t] = g;
        ret_out[base + t] = g + values[base + t];
    }
}

extern "C" void kernel_launch(void* const* d_in, const int* in_sizes, int n_in,
                              void* d_out, int out_size, void* d_ws, size_t ws_size,
                              hipStream_t stream) {
    const float* rewards    = (const float*)d_in[0];
    const float* values     = (const float*)d_in[1];
    const float* next_value = (const float*)d_in[2];
    const int*   done       = (const int*)d_in[3];

    const int B = in_sizes[2];               // next_value is [B]
    const int T = in_sizes[0] / B;           // rewards is [B, T]

    float* adv = (float*)d_out;
    float* ret = adv + (long)B * T;

    if (T == BLOCK * CHUNK) {
        const int grid = (B < GRID_TARGET) ? B : GRID_TARGET;
        gae_scan_kernel<<<grid, BLOCK, 0, stream>>>(
            rewards, values, next_value, done, adv, ret, B, T);
    } else {
        gae_naive_kernel<<<(B + 255) / 256, 256, 0, stream>>>(
            rewards, values, next_value, done, adv, ret, B, T);
    }
}